// Round 2
// baseline (9077.087 us; speedup 1.0000x reference)
//
#include <hip/hip_runtime.h>
#include <cstdint>

#define DEVI __device__ __forceinline__

typedef __bf16 bf16x8 __attribute__((ext_vector_type(8)));
typedef float f32x4 __attribute__((ext_vector_type(4)));

DEVI unsigned short f2b(float f) {
    unsigned int u = __builtin_bit_cast(unsigned int, f);
    unsigned int r = (u + 0x7FFFu + ((u >> 16) & 1u)) >> 16;
    return (unsigned short)r;
}
DEVI float b2f(unsigned short h) {
    unsigned int u = ((unsigned int)h) << 16;
    return __builtin_bit_cast(float, u);
}
DEVI float sigm(float x) { return 1.0f / (1.0f + __expf(-x)); }
DEVI float tanh_f(float x) {
    float e = __expf(-2.0f * fabsf(x));
    float r = (1.0f - e) / (1.0f + e);
    return x < 0.0f ? -r : r;
}

// async global->LDS, 16B per lane; LDS dest wave-uniform base (HW adds lane*16).
// Low 32 bits of a generic LDS address == LDS byte offset (4GB-aligned aperture).
DEVI void gload_lds16(const unsigned short* g, unsigned short* l) {
    typedef __attribute__((address_space(1))) void gv_t;
    typedef __attribute__((address_space(3))) void lv_t;
    gv_t* gp = (gv_t*)(uintptr_t)g;
    lv_t* lp = (lv_t*)(unsigned int)(uintptr_t)l;
    __builtin_amdgcn_global_load_lds(gp, lp, 16, 0, 0);
}

// ---------------- input transpose: (B,C,L) f32 -> xT (L+2, B, C) bf16, zero rows 0 and 129
__global__ void k_tin(const float* __restrict__ in, unsigned short* __restrict__ xT) {
    __shared__ float tile[32][33];
    int c0 = blockIdx.x * 32, t0 = blockIdx.y * 32, b = blockIdx.z;
    int tx = threadIdx.x, ty = threadIdx.y;
#pragma unroll
    for (int i = 0; i < 4; ++i) {
        int c = c0 + ty + i * 8;
        int t = t0 + tx;
        float v = 0.0f;
        if (t >= 1 && t <= 128) v = in[((size_t)b * 256 + c) * 128 + (t - 1)];
        tile[ty + i * 8][tx] = v;  // [c_local][t_local]
    }
    __syncthreads();
#pragma unroll
    for (int i = 0; i < 4; ++i) {
        int t = t0 + ty + i * 8;
        int c = c0 + tx;
        if (t < 130) xT[((size_t)t * 1024 + b) * 256 + c] = f2b(tile[tx][ty + i * 8]);
    }
}

// ---------------- weight transpose: w (K,N) f32 -> wt (N,K) bf16
__global__ void k_wt(const float* __restrict__ w, unsigned short* __restrict__ wt, int K, int N) {
    __shared__ float tile[32][33];
    int n0 = blockIdx.x * 32, k0 = blockIdx.y * 32;
    int tx = threadIdx.x, ty = threadIdx.y;
#pragma unroll
    for (int i = 0; i < 4; ++i)
        tile[ty + i * 8][tx] = w[(size_t)(k0 + ty + i * 8) * N + n0 + tx];  // [k_local][n_local]
    __syncthreads();
#pragma unroll
    for (int i = 0; i < 4; ++i)
        wt[(size_t)(n0 + ty + i * 8) * K + k0 + tx] = f2b(tile[tx][ty + i * 8]);
}

// ---------------- GEMM: C[M,N] = A[M,K] @ Wt[N,K]^T   (bf16 in, f32 acc)
// MODE 0: A row-major (strideA). MODE 1: layer-0 window mode, A = xT (130,1024,256), t += tbase.
#define BM 128
#define BN 128
#define BKg 64

template <int MODE, int F32OUT, int BIAS>
__global__ __launch_bounds__(256) void kgemm(const unsigned short* __restrict__ A,
                                             const unsigned short* __restrict__ Wt,
                                             void* __restrict__ Cout,
                                             const float* __restrict__ bias,
                                             int Mtiles, int Ntiles, int KT, int strideA,
                                             int strideB, int N, int tbase) {
    __shared__ unsigned short As[BM * BKg];
    __shared__ unsigned short Bs[BN * BKg];

    int nwg = Mtiles * Ntiles;  // always % 8 == 0 here
    int q = nwg >> 3;
    int orig = blockIdx.x;
    int wg = (orig & 7) * q + (orig >> 3);  // bijective XCD swizzle (nwg%8==0)
    int tn = wg % Ntiles, tm = wg / Ntiles;

    int tid = threadIdx.x;
    int wid = tid >> 6, lane = tid & 63;
    int srow = lane >> 3, skb = lane & 7;
    int lh = lane & 15, lq = lane >> 4;

    f32x4 acc[4][4] = {};
    int m0 = tm * BM;
    int t0 = m0 >> 10, b0 = m0 & 1023;  // window-mode decomposition (BM=128 divides 1024)
    int wr = wid >> 1, wc = wid & 1;

    for (int k0 = 0; k0 < KT; k0 += BKg) {
        const unsigned short* Abase;
        int rs;
        if (MODE == 1) {
            int w = k0 >> 8, c0 = k0 & 255;
            Abase = A + ((size_t)((tbase + t0 + w) * 1024 + b0)) * 256 + c0;
            rs = 256;
        } else {
            Abase = A + (size_t)m0 * strideA + k0;
            rs = strideA;
        }
        const unsigned short* Bbase = Wt + (size_t)(tn * BN) * strideB + k0;
#pragma unroll
        for (int c = 0; c < 4; ++c) {  // A tile, source pre-swizzled (both-sides rule)
            int chunk = c * 4 + wid;
            int row = chunk * 8 + srow;
            int kbs = skb ^ (row & 7);
            gload_lds16(Abase + (size_t)row * rs + kbs * 8, &As[chunk * 512]);
        }
#pragma unroll
        for (int c = 0; c < 4; ++c) {  // B tile
            int chunk = c * 4 + wid;
            int row = chunk * 8 + srow;
            int kbs = skb ^ (row & 7);
            gload_lds16(Bbase + (size_t)row * strideB + kbs * 8, &Bs[chunk * 512]);
        }
        __syncthreads();
#pragma unroll
        for (int kk = 0; kk < 2; ++kk) {
            bf16x8 af[4], bfv[4];
            int kc = kk * 4 + lq;  // k-block (k>>3)
#pragma unroll
            for (int i = 0; i < 4; ++i) {
                int m = wr * 64 + i * 16 + lh;
                af[i] = *(const bf16x8*)((const char*)As + m * 128 + ((kc ^ (m & 7)) * 16));
            }
#pragma unroll
            for (int j = 0; j < 4; ++j) {
                int n = wc * 64 + j * 16 + lh;
                bfv[j] = *(const bf16x8*)((const char*)Bs + n * 128 + ((kc ^ (n & 7)) * 16));
            }
#pragma unroll
            for (int i = 0; i < 4; ++i)
#pragma unroll
                for (int j = 0; j < 4; ++j)
                    acc[i][j] = __builtin_amdgcn_mfma_f32_16x16x32_bf16(af[i], bfv[j], acc[i][j], 0, 0, 0);
        }
        __syncthreads();
    }
#pragma unroll
    for (int i = 0; i < 4; ++i) {
#pragma unroll
        for (int j = 0; j < 4; ++j) {
            int colg = tn * BN + wc * 64 + j * 16 + lh;
            float bv = BIAS ? bias[colg] : 0.0f;
#pragma unroll
            for (int r = 0; r < 4; ++r) {
                int rowg = m0 + wr * 64 + i * 16 + lq * 4 + r;
                float v = acc[i][j][r] + bv;
                if (F32OUT)
                    ((float*)Cout)[(size_t)rowg * N + colg] = v;
                else
                    ((unsigned short*)Cout)[(size_t)rowg * N + colg] = f2b(v);
            }
        }
    }
}

// ---------------- recurrent LSTM phase, chunked [s0, s0+Tc).
// grid (32 row-blocks, 2 dirs), 512 threads (8 waves). Block owns 32 batch rows.
// h in swizzled LDS (carried via hst between chunks), c in regs (carried via cst).
__global__ __launch_bounds__(512) void klstm(const unsigned short* __restrict__ gxf,
                                             const unsigned short* __restrict__ gxb,
                                             const unsigned short* __restrict__ wtf,
                                             const unsigned short* __restrict__ wtb,
                                             const float* __restrict__ bf_,
                                             const float* __restrict__ bb_,
                                             unsigned short* __restrict__ xs_out,
                                             unsigned short* __restrict__ hst,
                                             float* __restrict__ cst,
                                             int I, int KS, int s0, int Tc) {
    __shared__ unsigned short h_lds[32 * 256];  // [row][col] bf16, XOR-swizzled, 16KB
    int dir = blockIdx.y;
    int b0 = blockIdx.x * 32;
    const unsigned short* gx = dir ? gxb : gxf;
    const unsigned short* wt = dir ? wtb : wtf;
    const float* bias = dir ? bb_ : bf_;
    const unsigned short* wh = wt + I;  // Wt[n][I + k], row stride KS

    int tid = threadIdx.x, wid = tid >> 6, lane = tid & 63;
    int lh = lane & 15, lq = lane >> 4;

    float c_reg[2][2][4] = {};
    if (s0 == 0) {
        for (int i = tid; i < 32 * 256; i += 512) h_lds[i] = 0;
    } else {
        for (int i = tid; i < 32 * 256; i += 512) {
            int row = i >> 8, col = i & 255;
            *(unsigned short*)((char*)h_lds + row * 512 + (((col >> 3) ^ (row & 7)) * 16) +
                               (col & 7) * 2) = hst[((size_t)dir * 1024 + b0 + row) * 256 + col];
        }
#pragma unroll
        for (int mf = 0; mf < 2; ++mf)
#pragma unroll
            for (int r = 0; r < 4; ++r)
#pragma unroll
                for (int p = 0; p < 2; ++p) {
                    int row = mf * 16 + lq * 4 + r;
                    int col = wid * 32 + p * 16 + lh;
                    c_reg[mf][p][r] = cst[((size_t)dir * 1024 + b0 + row) * 256 + col];
                }
    }
    float bia[2], big[2], bif[2], bio[2];
#pragma unroll
    for (int p = 0; p < 2; ++p) {
        int col = wid * 32 + p * 16 + lh;
        bia[p] = bias[col];
        big[p] = bias[256 + col];
        bif[p] = bias[512 + col];
        bio[p] = bias[768 + col];
    }
    __syncthreads();

    for (int s = s0; s < s0 + Tc; ++s) {
        int t = dir ? (127 - s) : s;
        int gloc = dir ? (s0 + Tc - 1 - s) : (s - s0);

        // A-fragments of h (16 ds_read_b128, swizzled)
        bf16x8 afr[2][8];
#pragma unroll
        for (int mf = 0; mf < 2; ++mf)
#pragma unroll
            for (int kf = 0; kf < 8; ++kf) {
                int m = mf * 16 + lh;
                int kc = kf * 4 + lq;
                afr[mf][kf] = *(const bf16x8*)((const char*)h_lds + m * 512 + ((kc ^ (m & 7)) * 16));
            }
        __syncthreads();  // (A) all reads done before this step's writes

        f32x4 acc[2][8] = {};
#pragma unroll
        for (int kf = 0; kf < 8; ++kf) {
#pragma unroll
            for (int nf = 0; nf < 8; ++nf) {
                int g = nf >> 1, p = nf & 1;
                int n = g * 256 + wid * 32 + p * 16 + lh;
                bf16x8 bfr = *(const bf16x8*)(wh + (size_t)n * KS + kf * 32 + lq * 8);
                acc[0][nf] = __builtin_amdgcn_mfma_f32_16x16x32_bf16(afr[0][kf], bfr, acc[0][nf], 0, 0, 0);
                acc[1][nf] = __builtin_amdgcn_mfma_f32_16x16x32_bf16(afr[1][kf], bfr, acc[1][nf], 0, 0, 0);
            }
        }

        // elementwise LSTM update (each lane owns 16 (row,col) cells)
#pragma unroll
        for (int mf = 0; mf < 2; ++mf) {
#pragma unroll
            for (int r = 0; r < 4; ++r) {
                int row = mf * 16 + lq * 4 + r;
                size_t gxrow = ((size_t)gloc * 1024 + b0 + row) * 1024;
#pragma unroll
                for (int p = 0; p < 2; ++p) {
                    int col = wid * 32 + p * 16 + lh;
                    float gi = acc[mf][0 + p][r] + b2f(gx[gxrow + col]) + bia[p];
                    float gg = acc[mf][2 + p][r] + b2f(gx[gxrow + 256 + col]) + big[p];
                    float gf = acc[mf][4 + p][r] + b2f(gx[gxrow + 512 + col]) + bif[p];
                    float go = acc[mf][6 + p][r] + b2f(gx[gxrow + 768 + col]) + bio[p];
                    float cv = sigm(gf + 1.0f) * c_reg[mf][p][r] + sigm(gi) * tanh_f(gg);
                    c_reg[mf][p][r] = cv;
                    float hv = sigm(go) * tanh_f(cv);
                    unsigned short hb = f2b(hv);
                    *(unsigned short*)((char*)h_lds + row * 512 + (((col >> 3) ^ (row & 7)) * 16) +
                                       (col & 7) * 2) = hb;
                    xs_out[((size_t)t * 1024 + b0 + row) * 512 + dir * 256 + col] = hb;
                }
            }
        }
        __syncthreads();  // (B) h writes visible for next step
    }

    // carry state out
    for (int i = tid; i < 32 * 256; i += 512) {
        int row = i >> 8, col = i & 255;
        hst[((size_t)dir * 1024 + b0 + row) * 256 + col] =
            *(const unsigned short*)((const char*)h_lds + row * 512 +
                                     (((col >> 3) ^ (row & 7)) * 16) + (col & 7) * 2);
    }
#pragma unroll
    for (int mf = 0; mf < 2; ++mf)
#pragma unroll
        for (int r = 0; r < 4; ++r)
#pragma unroll
            for (int p = 0; p < 2; ++p) {
                int row = mf * 16 + lq * 4 + r;
                int col = wid * 32 + p * 16 + lh;
                cst[((size_t)dir * 1024 + b0 + row) * 256 + col] = c_reg[mf][p][r];
            }
}

// ---------------- output transpose: tmp (L,B,O) f32 -> out (B,O,L) f32
__global__ void k_tout(const float* __restrict__ tmp, float* __restrict__ out) {
    __shared__ float tile[32][33];
    int o0 = blockIdx.x * 32, l0 = blockIdx.y * 32, b = blockIdx.z;
    int tx = threadIdx.x, ty = threadIdx.y;
#pragma unroll
    for (int i = 0; i < 4; ++i)
        tile[ty + i * 8][tx] = tmp[((size_t)(l0 + ty + i * 8) * 1024 + b) * 256 + o0 + tx];
    __syncthreads();
#pragma unroll
    for (int i = 0; i < 4; ++i)
        out[((size_t)b * 256 + o0 + ty + i * 8) * 128 + l0 + tx] = tile[tx][ty + i * 8];
}

extern "C" void kernel_launch(void* const* d_in, const int* in_sizes, int n_in,
                              void* d_out, int out_size, void* d_ws, size_t ws_size,
                              hipStream_t stream) {
    const float* inp  = (const float*)d_in[0];
    const float* wfw0 = (const float*)d_in[1];
    const float* bfw0 = (const float*)d_in[2];
    const float* wbw0 = (const float*)d_in[3];
    const float* bbw0 = (const float*)d_in[4];
    const float* wfwr = (const float*)d_in[5];
    const float* bfwr = (const float*)d_in[6];
    const float* wbwr = (const float*)d_in[7];
    const float* bbwr = (const float*)d_in[8];
    const float* wout = (const float*)d_in[9];
    const float* bout = (const float*)d_in[10];

    char* ws = (char*)d_ws;
    size_t o = 0;
    auto alloc = [&](size_t bytes) {
        void* p = ws + o;
        o += (bytes + 255) & ~(size_t)255;
        return p;
    };
    unsigned short* wt0f = (unsigned short*)alloc((size_t)1024 * 1024 * 2);
    unsigned short* wt0b = (unsigned short*)alloc((size_t)1024 * 1024 * 2);
    unsigned short* wt1f = (unsigned short*)alloc((size_t)1024 * 768 * 2);
    unsigned short* wt1b = (unsigned short*)alloc((size_t)1024 * 768 * 2);
    unsigned short* wt2f = (unsigned short*)alloc((size_t)1024 * 768 * 2);
    unsigned short* wt2b = (unsigned short*)alloc((size_t)1024 * 768 * 2);
    unsigned short* wto  = (unsigned short*)alloc((size_t)256 * 512 * 2);
    unsigned short* hst  = (unsigned short*)alloc((size_t)2 * 1024 * 256 * 2);
    float*          cst  = (float*)alloc((size_t)2 * 1024 * 256 * 4);
    unsigned short* xsa  = (unsigned short*)alloc((size_t)131072 * 512 * 2);
    unsigned short* xsb  = (unsigned short*)alloc((size_t)131072 * 512 * 2);
    // aliases into xsb's region (lifetime-disjoint):
    unsigned short* xT   = xsb;          // used only during layer-0 GEMMs
    float*          otmp = (float*)xsb;  // used only after layer-2 GEMMs consumed xsb

    // gx chunk buffers: pick largest Tc (power of 2, <=128) fitting remaining ws
    size_t base = o;
    int Tc = 128;
    while (Tc > 1 && base + (size_t)Tc * 4 * 1024 * 1024 > ws_size) Tc >>= 1;
    unsigned short* gxf = (unsigned short*)alloc((size_t)Tc * 1024 * 1024 * 2);
    unsigned short* gxb = (unsigned short*)alloc((size_t)Tc * 1024 * 1024 * 2);

    dim3 tb(32, 8);
    k_tin<<<dim3(8, 5, 1024), tb, 0, stream>>>(inp, xT);
    k_wt<<<dim3(32, 32), tb, 0, stream>>>(wfw0, wt0f, 1024, 1024);
    k_wt<<<dim3(32, 32), tb, 0, stream>>>(wbw0, wt0b, 1024, 1024);
    k_wt<<<dim3(32, 24), tb, 0, stream>>>(wfwr, wt1f, 768, 1024);
    k_wt<<<dim3(32, 24), tb, 0, stream>>>(wbwr, wt1b, 768, 1024);
    k_wt<<<dim3(32, 24), tb, 0, stream>>>(wfwr + (size_t)768 * 1024, wt2f, 768, 1024);
    k_wt<<<dim3(32, 24), tb, 0, stream>>>(wbwr + (size_t)768 * 1024, wt2b, 768, 1024);
    k_wt<<<dim3(8, 16), tb, 0, stream>>>(wout, wto, 512, 256);

    int Mt = Tc * 8, grid = Tc * 64;
    // ---- layer 0 (window-mode GEMMs, K=768, weight stride 1024)
    for (int s0 = 0; s0 < 128; s0 += Tc) {
        int tbw = 128 - s0 - Tc;
        kgemm<1, 0, 0><<<grid, 256, 0, stream>>>(xT, wt0f, gxf, nullptr, Mt, 8, 768, 256, 1024, 1024, s0);
        kgemm<1, 0, 0><<<grid, 256, 0, stream>>>(xT, wt0b, gxb, nullptr, Mt, 8, 768, 256, 1024, 1024, tbw);
        klstm<<<dim3(32, 2), 512, 0, stream>>>(gxf, gxb, wt0f, wt0b, bfw0, bbw0, xsa, hst, cst, 768, 1024, s0, Tc);
    }
    // ---- layer 1 (K=512, weight stride 768)
    for (int s0 = 0; s0 < 128; s0 += Tc) {
        int tbw = 128 - s0 - Tc;
        kgemm<0, 0, 0><<<grid, 256, 0, stream>>>(xsa + (size_t)s0 * 1024 * 512, wt1f, gxf, nullptr, Mt, 8, 512, 512, 768, 1024, 0);
        kgemm<0, 0, 0><<<grid, 256, 0, stream>>>(xsa + (size_t)tbw * 1024 * 512, wt1b, gxb, nullptr, Mt, 8, 512, 512, 768, 1024, 0);
        klstm<<<dim3(32, 2), 512, 0, stream>>>(gxf, gxb, wt1f, wt1b, bfwr, bbwr, xsb, hst, cst, 512, 768, s0, Tc);
    }
    // ---- layer 2
    for (int s0 = 0; s0 < 128; s0 += Tc) {
        int tbw = 128 - s0 - Tc;
        kgemm<0, 0, 0><<<grid, 256, 0, stream>>>(xsb + (size_t)s0 * 1024 * 512, wt2f, gxf, nullptr, Mt, 8, 512, 512, 768, 1024, 0);
        kgemm<0, 0, 0><<<grid, 256, 0, stream>>>(xsb + (size_t)tbw * 1024 * 512, wt2b, gxb, nullptr, Mt, 8, 512, 512, 768, 1024, 0);
        klstm<<<dim3(32, 2), 512, 0, stream>>>(gxf, gxb, wt2f, wt2b, bfwr + 1024, bbwr + 1024, xsa, hst, cst, 512, 768, s0, Tc);
    }
    // ---- output projection (f32 + bias) then transpose to (B,O,L)
    kgemm<0, 1, 1><<<2048, 256, 0, stream>>>(xsa, wto, otmp, bout, 1024, 2, 512, 512, 512, 256, 0);
    k_tout<<<dim3(8, 4, 1024), tb, 0, stream>>>(otmp, (float*)d_out);
}